// Round 4
// baseline (245.690 us; speedup 1.0000x reference)
//
#include <hip/hip_runtime.h>
#include <hip/hip_bf16.h>
#include <stdint.h>

// Problem constants (fixed by setup_inputs)
#define FCB 2            // codebooks
#define BB 16            // batch
#define NN 256           // tokens per (b)
#define EDIM 1024
#define CC 512           // channels per codebook
#define NE 4096          // prototypes per codebook
#define TOKENS (BB*FCB*NN)   // 8192
#define ROWS (FCB*NE)        // 8192 emb rows
#define OUT_LOSS (BB*NN*EDIM)   // 4194304 (also the element count for the mean)
#define OUT_IDX  (OUT_LOSS + 1)
#define NR 128           // 32-row tiles per codebook (4096/32), both matrices

typedef __attribute__((ext_vector_type(8))) short bf16x8;    // MFMA A/B frag (4 VGPR)
typedef __attribute__((ext_vector_type(16))) float f32x16;   // 32x32 MFMA C/D frag

// monotonic float->uint mapping for packed atomic argmax
__device__ __forceinline__ unsigned int ford(float v) {
    unsigned int u = __float_as_uint(v);
    return (u & 0x80000000u) ? ~u : (u | 0x80000000u);
}

// ---------------------------------------------------------------------------
// ws layout:
//   [0]        inv_norm   8192 f32   (32 KB)
//   [32768]    best       8192 u64   (64 KB)
//   [98304]    loss_tok   8192 f32   (32 KB)
//   [131072]   z_hi  2*4096*512 bf16 (8 MB)   packed 32-row chunk order
//   [+8MB]     z_lo
//   [+16MB]    e_hi
//   [+24MB]    e_lo
// Packed layout (per part): chunk (f, R32, H) of 1024 B:
//   elem = ((f*NR + R32)*32 + H)*512 + q*256 + mm*8 + j
//   row = R32*32 + mm, k = H*16 + q*8 + j.
// One chunk == one wave-wide global_load_lds (64 lanes x 16 B), and the
// 32x32x16 A/B fragment read (m=lane&31, k=(lane>>5)*8+j) is exactly
// lds_base + lane*16 within a chunk -> conflict-free lane-linear.
// ---------------------------------------------------------------------------

// ---- pack kernel: fp32 -> (hi, lo) bf16 split, both matrices, one launch ---
__global__ __launch_bounds__(256) void pack_split(
    const float* __restrict__ z, const float* __restrict__ emb,
    short* __restrict__ z_hi, short* __restrict__ z_lo,
    short* __restrict__ e_hi, short* __restrict__ e_lo)
{
    int bid = blockIdx.x;
    const float* src; short* hi; short* lo; int RS, FRO, FCO;
    if (bid < 2048) { src = z;   hi = z_hi; lo = z_lo; RS = EDIM; FRO = 0;  FCO = CC; }
    else            { src = emb; hi = e_hi; lo = e_lo; RS = CC;   FRO = NE; FCO = 0; bid -= 2048; }
    int gid = bid * 256 + threadIdx.x;        // [0, 524288)
    int chunk = gid >> 6;                     // (f*NR + R32)*32 + H
    int mm = gid & 31;
    int q  = (gid >> 5) & 1;
    int f  = chunk >> 12;
    int R32 = (chunk >> 5) & 127;
    int H  = chunk & 31;
    int row = R32 * 32 + mm;
    const float* s = src + (size_t)(f * FRO + row) * RS + f * FCO + H * 16 + q * 8;
    float4 v0 = *(const float4*)s;
    float4 v1 = *(const float4*)(s + 4);
    float vv[8] = {v0.x, v0.y, v0.z, v0.w, v1.x, v1.y, v1.z, v1.w};
    bf16x8 h8, l8;
    #pragma unroll
    for (int j = 0; j < 8; ++j) {
        __hip_bfloat16 hb = __float2bfloat16(vv[j]);
        float r = vv[j] - __bfloat162float(hb);   // exact residual
        __hip_bfloat16 lb = __float2bfloat16(r);
        h8[j] = *(short*)&hb;
        l8[j] = *(short*)&lb;
    }
    *(bf16x8*)(hi + (size_t)gid * 8) = h8;
    *(bf16x8*)(lo + (size_t)gid * 8) = l8;
}

// ---- init: inv_norm per emb row; zero best[] -------------------------------
__global__ __launch_bounds__(256) void init_kernel(
    const float* __restrict__ emb, float* __restrict__ inv_norm,
    unsigned long long* __restrict__ best)
{
    int r = blockIdx.x;            // 0..8191
    int tid = threadIdx.x;
    const float* row = emb + (size_t)r * CC;
    float a = row[tid], b = row[tid + 256];
    float ss = a*a + b*b;
    #pragma unroll
    for (int off = 32; off; off >>= 1) ss += __shfl_down(ss, off);
    __shared__ float part[4];
    if ((tid & 63) == 0) part[tid >> 6] = ss;
    __syncthreads();
    if (tid == 0) {
        float t = part[0] + part[1] + part[2] + part[3];
        inv_norm[r] = 1.0f / fmaxf(sqrtf(t), 1e-12f);
        best[r] = 0ull;                 // any real packed value beats 0
    }
}

// ---- bf16x3 split MFMA GEMM (32x32x16) + fused argmax ----------------------
// 256x128 block, 4 waves (2x2); wave = 128(m) x 64(n) = 4x2 tiles of 32x32.
// C = Ah*Bh + Ah*Bl + Al*Bh  (dropped Al*Bl ~1e-7 on cos).
__global__ __launch_bounds__(256, 2) void gemm_mfma(
    const short* __restrict__ zh, const short* __restrict__ zl,
    const short* __restrict__ eh, const short* __restrict__ el,
    const float* __restrict__ inv_norm, unsigned long long* __restrict__ best)
{
    __shared__ char smem[49152];      // A_hi 16K | A_lo 16K | B_hi 8K | B_lo 8K
    const int f  = blockIdx.z;
    const int t0 = blockIdx.y * 256;  // token base within codebook
    const int m0 = blockIdx.x * 128;  // proto base within codebook
    const int tid  = threadIdx.x;
    const int wave = tid >> 6, lane = tid & 63;
    const int wm = wave & 1, wn = wave >> 1;

    const short* srcs[4] = {zh, zl, eh, el};

    f32x16 acc[4][2] = {};

    for (int step = 0; step < 16; ++step) {
        const int H0 = step * 2;
        __syncthreads();              // previous compute done before overwrite
        // 48 chunks of 1 KB per step: A_hi 16, A_lo 16, B_hi 8, B_lo 8
        #pragma unroll
        for (int i = 0; i < 12; ++i) {
            int c = wave * 12 + i;
            int part, local, ldsoff, R32;
            if (c < 32) { part = c >> 4; local = c & 15; ldsoff = part * 16384 + local * 1024;
                          R32 = (t0 >> 5) + (local >> 1); }
            else        { part = 2 + ((c - 32) >> 3); local = (c - 32) & 7;
                          ldsoff = 32768 + (part - 2) * 8192 + local * 1024;
                          R32 = (m0 >> 5) + (local >> 1); }
            int h = local & 1;
            const short* g = srcs[part]
                + (((size_t)f * NR + R32) * 32 + H0 + h) * 512 + (size_t)lane * 8;
            __builtin_amdgcn_global_load_lds(
                (const __attribute__((address_space(1))) void*)g,
                (__attribute__((address_space(3))) void*)(smem + ldsoff),
                16, 0, 0);
        }
        __syncthreads();              // staged data visible to all waves

        #pragma unroll
        for (int h = 0; h < 2; ++h) {
            bf16x8 ah[4], al[4], bh[2], bl[2];
            #pragma unroll
            for (int i = 0; i < 4; ++i) {
                int ta = wm * 4 + i;
                ah[i] = *(const bf16x8*)(smem + 0     + (ta*2 + h) * 1024 + lane * 16);
                al[i] = *(const bf16x8*)(smem + 16384 + (ta*2 + h) * 1024 + lane * 16);
            }
            #pragma unroll
            for (int j = 0; j < 2; ++j) {
                int tb = wn * 2 + j;
                bh[j] = *(const bf16x8*)(smem + 32768 + (tb*2 + h) * 1024 + lane * 16);
                bl[j] = *(const bf16x8*)(smem + 40960 + (tb*2 + h) * 1024 + lane * 16);
            }
            #pragma unroll
            for (int i = 0; i < 4; ++i)
                #pragma unroll
                for (int j = 0; j < 2; ++j) {
                    acc[i][j] = __builtin_amdgcn_mfma_f32_32x32x16_bf16(ah[i], bh[j], acc[i][j], 0, 0, 0);
                    acc[i][j] = __builtin_amdgcn_mfma_f32_32x32x16_bf16(ah[i], bl[j], acc[i][j], 0, 0, 0);
                    acc[i][j] = __builtin_amdgcn_mfma_f32_32x32x16_bf16(al[i], bh[j], acc[i][j], 0, 0, 0);
                }
        }
    }

    // ---- fused argmax epilogue ----
    // 32x32 C/D layout: col(N) = lane&31, row(M) = (reg&3) + 8*(reg>>2) + 4*(lane>>5)
    float inm[2]; int nid[2];
    #pragma unroll
    for (int j = 0; j < 2; ++j) {
        nid[j] = m0 + wn * 64 + j * 32 + (lane & 31);
        inm[j] = inv_norm[f * NE + nid[j]];
    }

    #pragma unroll
    for (int i = 0; i < 4; ++i) {
        #pragma unroll
        for (int r = 0; r < 16; ++r) {
            float v0 = acc[i][0][r] * inm[0];
            float v1 = acc[i][1][r] * inm[1];
            float v; int id;
            if (v1 > v0 || (v1 == v0 && nid[1] < nid[0])) { v = v1; id = nid[1]; }
            else                                          { v = v0; id = nid[0]; }
            // reduce across the 32 lanes of this half-wave (same row set)
            #pragma unroll
            for (int off = 16; off; off >>= 1) {
                float ov = __shfl_down(v, off, 32);
                int   oi = __shfl_down(id, off, 32);
                if (ov > v || (ov == v && oi < id)) { v = ov; id = oi; }
            }
            if ((lane & 31) == 0) {
                int row = (r & 3) + 8 * (r >> 2) + 4 * (lane >> 5);
                int u = t0 + wm * 128 + i * 32 + row;
                int b = u >> 8, n = u & 255;
                int gt = ((b * FCB + f) << 8) + n;   // global token id (b,f,n)
                unsigned long long p = ((unsigned long long)ford(v) << 32)
                                     | (unsigned int)(~(unsigned int)id);
                atomicMax(best + gt, p);
            }
        }
    }
}

// ---- epilogue: one wave per token, float4, per-token loss (no atomics) -----
__global__ __launch_bounds__(256) void epilogue_kernel(
    const float* __restrict__ z, const float* __restrict__ emb,
    const float* __restrict__ inv_norm, const unsigned long long* __restrict__ best,
    float* __restrict__ out, float* __restrict__ loss_tok)
{
    int t = blockIdx.x * 4 + (threadIdx.x >> 6);   // global token (b,f,n)
    int lane = threadIdx.x & 63;
    int n = t & 255;
    int f = (t >> 8) & 1;
    int b = t >> 9;
    unsigned long long p = best[t];
    int idx = (int)(~(unsigned int)p);         // in [0, 4096): codebook-0 rows (faithful quirk)
    const float* zrow = z + ((size_t)(b*NN + n))*EDIM + f*CC;
    const float* erow = emb + (size_t)idx * CC;
    float inm = inv_norm[idx];
    float* orow = out + ((size_t)(b*NN + n))*EDIM + f*CC;
    float s1 = 0.f, s2 = 0.f;
    #pragma unroll
    for (int h = 0; h < 2; ++h) {
        int c = h * 256 + lane * 4;            // coalesced float4 per lane
        float4 zv = *(const float4*)(zrow + c);
        float4 ev = *(const float4*)(erow + c);
        ev.x *= inm; ev.y *= inm; ev.z *= inm; ev.w *= inm;
        *(float4*)(orow + c) = ev;             // z_q_st forward == z_q
        s1 = fmaf(zv.x, zv.x, fmaf(zv.y, zv.y, fmaf(zv.z, zv.z, fmaf(zv.w, zv.w, s1))));
        s2 = fmaf(zv.x, ev.x, fmaf(zv.y, ev.y, fmaf(zv.z, ev.z, fmaf(zv.w, ev.w, s2))));
    }
    #pragma unroll
    for (int off = 32; off; off >>= 1) {
        s1 += __shfl_down(s1, off);
        s2 += __shfl_down(s2, off);
    }
    if (lane == 0) {
        float cosv = s2 / fmaxf(sqrtf(s1), 1e-12f);   // zn . z_q
        loss_tok[t] = 2.0f - 2.0f * cosv;
        out[OUT_IDX + t] = (float)idx;                // indices read back as float
    }
}

// ---- final: sum per-token losses -> out[OUT_LOSS] --------------------------
__global__ __launch_bounds__(256) void loss_reduce(
    const float* __restrict__ loss_tok, float* __restrict__ out)
{
    int tid = threadIdx.x;
    float s = 0.f;
    #pragma unroll
    for (int h = 0; h < 32; ++h) s += loss_tok[h * 256 + tid];
    #pragma unroll
    for (int off = 32; off; off >>= 1) s += __shfl_down(s, off);
    __shared__ float part[4];
    if ((tid & 63) == 0) part[tid >> 6] = s;
    __syncthreads();
    if (tid == 0) {
        float t = part[0] + part[1] + part[2] + part[3];
        out[OUT_LOSS] = t * (1.25f / (float)OUT_LOSS);
    }
}

extern "C" void kernel_launch(void* const* d_in, const int* in_sizes, int n_in,
                              void* d_out, int out_size, void* d_ws, size_t ws_size,
                              hipStream_t stream) {
    const float* z   = (const float*)d_in[0];
    const float* emb = (const float*)d_in[1];
    float* out = (float*)d_out;

    char* ws = (char*)d_ws;
    float* inv_norm = (float*)ws;                                  // 32 KB
    unsigned long long* best = (unsigned long long*)(ws + 32768);  // 64 KB
    float* loss_tok = (float*)(ws + 98304);                        // 32 KB
    const size_t PART = (size_t)FCB * NE * CC;                     // 4 Mi elems
    short* z_hi = (short*)(ws + 131072);
    short* z_lo = z_hi + PART;
    short* e_hi = z_lo + PART;
    short* e_lo = e_hi + PART;
    // ws needed: 128 KB + 4 * 8 MB = ~33.7 MB

    pack_split<<<4096, 256, 0, stream>>>(z, emb, z_hi, z_lo, e_hi, e_lo);
    init_kernel<<<ROWS, 256, 0, stream>>>(emb, inv_norm, best);
    gemm_mfma<<<dim3(NE/128, NE/256, FCB), 256, 0, stream>>>(
        z_hi, z_lo, e_hi, e_lo, inv_norm, best);
    epilogue_kernel<<<TOKENS/4, 256, 0, stream>>>(z, emb, inv_norm, best, out, loss_tok);
    loss_reduce<<<1, 256, 0, stream>>>(loss_tok, out);
}

// Round 5
// 162.845 us; speedup vs baseline: 1.5087x; 1.5087x over previous
//
#include <hip/hip_runtime.h>
#include <hip/hip_bf16.h>
#include <stdint.h>

// Problem constants (fixed by setup_inputs)
#define FCB 2            // codebooks
#define BB 16            // batch
#define NN 256           // tokens per (b)
#define EDIM 1024
#define CC 512           // channels per codebook
#define NE 4096          // prototypes per codebook
#define TOKENS (BB*FCB*NN)   // 8192
#define ROWS (FCB*NE)        // 8192 emb rows
#define OUT_LOSS (BB*NN*EDIM)   // 4194304 (also the element count for the mean)
#define OUT_IDX  (OUT_LOSS + 1)
#define MARGIN 0.15f     // rescore margin in normalized-score units (~94 sigma of bf16 noise)

typedef __attribute__((ext_vector_type(8))) short bf16x8;   // MFMA A/B frag (4 VGPRs)
typedef __attribute__((ext_vector_type(4))) float f32x4;    // 16x16 MFMA C/D frag

// monotonic float<->uint mapping for packed argmax
__device__ __forceinline__ unsigned int ford(float v) {
    unsigned int u = __float_as_uint(v);
    return (u & 0x80000000u) ? ~u : (u | 0x80000000u);
}
__device__ __forceinline__ float unford(unsigned int u) {
    unsigned int b = (u & 0x80000000u) ? (u & 0x7fffffffu) : ~u;
    return __uint_as_float(b);
}

// ---------------------------------------------------------------------------
// ws layout:
//   [0]        inv_norm  8192 f32                      (32 KB)
//   [32768]    cand      8192 tok x 64 slots x 2 u64   (8 MB)   top-2 per 64-col group
//   [32768+8M] loss_tok  8192 f32                      (32 KB)
//   [+32KB]    z_hi      2*4096*512 bf16               (8 MB)   fragment-packed
//   [+8MB]     e_hi      2*4096*512 bf16               (8 MB)
// Packed layout: elem = ((f*256 + R)*64 + Q)*128 + m*8 + j
//   (R = 16-row tile, Q = 8-elem k-chunk, m = row-in-tile, j = elem).
//   Both the global_load_lds staging and ds_read_b128 fragment reads are
//   lane-linear (lane <-> 16 B), conflict-free.  (R3-proven layout.)
// ---------------------------------------------------------------------------

// ---- init: inv_norm per emb row (deterministic) ----------------------------
__global__ __launch_bounds__(256) void init_kernel(
    const float* __restrict__ emb, float* __restrict__ inv_norm)
{
    int r = blockIdx.x;            // 0..8191
    int tid = threadIdx.x;
    const float* row = emb + (size_t)r * CC;
    float a = row[tid], b = row[tid + 256];
    float ss = a*a + b*b;
    #pragma unroll
    for (int off = 32; off; off >>= 1) ss += __shfl_down(ss, off);
    __shared__ float part[4];
    if ((tid & 63) == 0) part[tid >> 6] = ss;
    __syncthreads();
    if (tid == 0) {
        float t = part[0] + part[1] + part[2] + part[3];
        inv_norm[r] = 1.0f / fmaxf(sqrtf(t), 1e-12f);
    }
}

// ---- pack: fp32 -> bf16 hi, fragment-packed, both matrices one launch ------
__global__ __launch_bounds__(256) void pack_hi(
    const float* __restrict__ z, const float* __restrict__ emb,
    short* __restrict__ z_hi, short* __restrict__ e_hi)
{
    int bid = blockIdx.x;
    const float* src; short* hi; int RS, FRO, FCO;
    if (bid < 2048) { src = z;   hi = z_hi; RS = EDIM; FRO = 0;  FCO = CC; }
    else            { src = emb; hi = e_hi; RS = CC;   FRO = NE; FCO = 0; bid -= 2048; }
    int u = bid * 256 + threadIdx.x;          // [0, 524288)
    int m = u & 15;
    int Q = (u >> 4) & 63;
    int R = (u >> 10) & 255;
    int f = u >> 18;
    int row = R * 16 + m;
    const float* s = src + (size_t)(f * FRO + row) * RS + f * FCO + Q * 8;
    float4 v0 = *(const float4*)s;
    float4 v1 = *(const float4*)(s + 4);
    float vv[8] = {v0.x, v0.y, v0.z, v0.w, v1.x, v1.y, v1.z, v1.w};
    bf16x8 h8;
    #pragma unroll
    for (int j = 0; j < 8; ++j) {
        __hip_bfloat16 hb = __float2bfloat16(vv[j]);
        h8[j] = *(short*)&hb;
    }
    *(bf16x8*)(hi + (size_t)u * 8) = h8;
}

// ---- 1-product bf16 MFMA GEMM + per-token top-2-per-64col selection --------
// 128x128 block, 4 waves (2x2), wave = 64x64 = 4x4 tiles of 16x16x32.
__global__ __launch_bounds__(256, 3) void gemm_sel(
    const short* __restrict__ zh, const short* __restrict__ eh,
    const float* __restrict__ inv_norm, unsigned long long* __restrict__ cand)
{
    __shared__ char smem[16384];      // A 8K | B 8K
    const int f  = blockIdx.z;
    const int t0 = blockIdx.y * 128;  // token base within codebook
    const int m0 = blockIdx.x * 128;  // proto base within codebook
    const int tid  = threadIdx.x;
    const int wave = tid >> 6, lane = tid & 63;
    const int wm = wave & 1, wn = wave >> 1;

    f32x4 acc[4][4] = {};

    for (int step = 0; step < 16; ++step) {
        const int qb = step * 4;      // k-chunk base (K = qb*8)
        __syncthreads();              // previous compute done before overwrite
        // 16 chunks of 1 KB: A tiles 0..7, B tiles 8..15; wave w stages 4
        #pragma unroll
        for (int i = 0; i < 4; ++i) {
            int c = wave * 4 + i;
            const short* gsrc = (c < 8) ? zh : eh;
            int R = (c < 8) ? ((t0 >> 4) + c) : ((m0 >> 4) + (c - 8));
            const short* g = gsrc
                + (((size_t)f * 256 + R) * 64 + qb) * 128 + (size_t)lane * 8;
            __builtin_amdgcn_global_load_lds(
                (const __attribute__((address_space(1))) void*)g,
                (__attribute__((address_space(3))) void*)(smem + c * 1024),
                16, 0, 0);
        }
        __syncthreads();              // staged data visible to all waves

        bf16x8 ah[4], bh[4];
        #pragma unroll
        for (int i = 0; i < 4; ++i) {
            ah[i] = *(const bf16x8*)(smem + (wm * 4 + i) * 1024 + lane * 16);
            bh[i] = *(const bf16x8*)(smem + 8192 + (wn * 4 + i) * 1024 + lane * 16);
        }
        #pragma unroll
        for (int i = 0; i < 4; ++i)
            #pragma unroll
            for (int j2 = 0; j2 < 4; ++j2)
                acc[i][j2] = __builtin_amdgcn_mfma_f32_16x16x32_bf16(ah[i], bh[j2], acc[i][j2], 0, 0, 0);
    }

    // ---- selection epilogue: per token, top-2 over this wave's 64 cols ----
    // C/D layout (16x16x32): col = lane&15, row = (lane>>4)*4 + reg
    float inm[4]; int nid[4];
    #pragma unroll
    for (int j2 = 0; j2 < 4; ++j2) {
        nid[j2] = m0 + wn * 64 + j2 * 16 + (lane & 15);
        inm[j2] = inv_norm[f * NE + nid[j2]];
    }

    #pragma unroll
    for (int i = 0; i < 4; ++i) {
        #pragma unroll
        for (int r = 0; r < 4; ++r) {
            // lane-local top-2 over the 4 j2 columns
            unsigned long long p1 = 0ull, p2 = 0ull;
            #pragma unroll
            for (int j2 = 0; j2 < 4; ++j2) {
                float w = acc[i][j2][r] * inm[j2];
                unsigned long long pw = ((unsigned long long)ford(w) << 32)
                                      | (unsigned int)(~(unsigned int)nid[j2]);
                if (pw > p1) { p2 = p1; p1 = pw; }
                else if (pw > p2) p2 = pw;
            }
            // merge top-2 across the 16 contiguous lanes of this token row
            #pragma unroll
            for (int off = 8; off; off >>= 1) {
                unsigned long long q1 = __shfl_down(p1, off, 16);
                unsigned long long q2 = __shfl_down(p2, off, 16);
                if (q1 > p1) { unsigned long long t = p1; p1 = q1; p2 = (t > q2) ? t : q2; }
                else         { p2 = (p2 > q1) ? p2 : q1; }
            }
            if ((lane & 15) == 0) {
                int u = t0 + wm * 64 + i * 16 + (lane >> 4) * 4 + r;
                int b = u >> 8, n = u & 255;
                int gt = ((b * FCB + f) << 8) + n;   // global token id (b,f,n)
                // single writer per slot: no atomics, no init needed
                unsigned long long* slot =
                    cand + (((size_t)gt << 6) + (blockIdx.x << 1) + wn) * 2;
                slot[0] = p1; slot[1] = p2;
            }
        }
    }
}

// ---- rescore + output epilogue: one wave per token -------------------------
__global__ __launch_bounds__(256) void rescore_epilogue(
    const float* __restrict__ z, const float* __restrict__ emb,
    const float* __restrict__ inv_norm, const unsigned long long* __restrict__ cand,
    float* __restrict__ out, float* __restrict__ loss_tok)
{
    int t = blockIdx.x * 4 + (threadIdx.x >> 6);   // global token (b,f,n)
    int lane = threadIdx.x & 63;
    int n = t & 255;
    int f = (t >> 8) & 1;
    int b = t >> 9;
    const float* zrow = z + ((size_t)(b*NN + n))*EDIM + f*CC;
    // lane's 8 z elements (contiguous per lane -> coalesced wave-wide)
    float4 za = *(const float4*)(zrow + lane * 8);
    float4 zb = *(const float4*)(zrow + lane * 8 + 4);

    // 128 candidates: lane reads one slot (2 packed u64)
    const unsigned long long* slot = cand + (((size_t)t << 6) + lane) * 2;
    unsigned long long c1 = slot[0], c2 = slot[1];

    // wave max of approx scores
    unsigned long long m1 = (c1 > c2) ? c1 : c2;
    #pragma unroll
    for (int off = 32; off; off >>= 1) {
        unsigned long long o = __shfl_xor(m1, off);
        if (o > m1) m1 = o;
    }
    float vmax = unford((unsigned int)(m1 >> 32));
    float thr = vmax - MARGIN;

    unsigned long long bestp = 0ull;
    #pragma unroll
    for (int rnd = 0; rnd < 2; ++rnd) {
        unsigned long long p = rnd ? c2 : c1;
        float v = unford((unsigned int)(p >> 32));
        unsigned long long mask = __ballot(v > thr);
        while (mask) {
            int src = __ffsll((long long)mask) - 1;
            mask &= mask - 1;
            unsigned long long cp = __shfl(p, src);
            int idx = (int)(~(unsigned int)cp);            // proto index [0,4096)
            const float* er = emb + ((size_t)(f * NE + idx)) * CC;
            float4 ea = *(const float4*)(er + lane * 8);
            float4 eb = *(const float4*)(er + lane * 8 + 4);
            float d = za.x*ea.x + za.y*ea.y + za.z*ea.z + za.w*ea.w
                    + zb.x*eb.x + zb.y*eb.y + zb.z*eb.z + zb.w*eb.w;
            #pragma unroll
            for (int off = 32; off; off >>= 1) d += __shfl_xor(d, off);
            float vex = d * inv_norm[f * NE + idx];        // all lanes identical
            unsigned long long pex = ((unsigned long long)ford(vex) << 32)
                                   | (unsigned int)(~(unsigned int)idx);
            if (pex > bestp) bestp = pex;
        }
    }
    int idxb = (int)(~(unsigned int)bestp);    // exact argmax (tie -> lower idx)

    // ---- output: z_q gather (codebook-0 row, faithful quirk) + loss -------
    const float* er0 = emb + (size_t)idxb * CC;
    float inm0 = inv_norm[idxb];
    float* orow = out + ((size_t)(b*NN + n))*EDIM + f*CC;
    float4 ea = *(const float4*)(er0 + lane * 8);
    float4 eb = *(const float4*)(er0 + lane * 8 + 4);
    ea.x *= inm0; ea.y *= inm0; ea.z *= inm0; ea.w *= inm0;
    eb.x *= inm0; eb.y *= inm0; eb.z *= inm0; eb.w *= inm0;
    *(float4*)(orow + lane * 8) = ea;
    *(float4*)(orow + lane * 8 + 4) = eb;
    float s1 = za.x*za.x + za.y*za.y + za.z*za.z + za.w*za.w
             + zb.x*zb.x + zb.y*zb.y + zb.z*zb.z + zb.w*zb.w;
    float s2 = za.x*ea.x + za.y*ea.y + za.z*ea.z + za.w*ea.w
             + zb.x*eb.x + zb.y*eb.y + zb.z*eb.z + zb.w*eb.w;
    #pragma unroll
    for (int off = 32; off; off >>= 1) {
        s1 += __shfl_xor(s1, off);
        s2 += __shfl_xor(s2, off);
    }
    if (lane == 0) {
        float cosv = s2 / fmaxf(sqrtf(s1), 1e-12f);   // zn . z_q
        loss_tok[t] = 2.0f - 2.0f * cosv;
        out[OUT_IDX + t] = (float)idxb;               // indices read back as float
    }
}

// ---- final: sum per-token losses -> out[OUT_LOSS] --------------------------
__global__ __launch_bounds__(256) void loss_reduce(
    const float* __restrict__ loss_tok, float* __restrict__ out)
{
    int tid = threadIdx.x;
    float s = 0.f;
    #pragma unroll
    for (int h = 0; h < 32; ++h) s += loss_tok[h * 256 + tid];
    #pragma unroll
    for (int off = 32; off; off >>= 1) s += __shfl_down(s, off);
    __shared__ float part[4];
    if ((tid & 63) == 0) part[tid >> 6] = s;
    __syncthreads();
    if (tid == 0) {
        float t = part[0] + part[1] + part[2] + part[3];
        out[OUT_LOSS] = t * (1.25f / (float)OUT_LOSS);
    }
}

extern "C" void kernel_launch(void* const* d_in, const int* in_sizes, int n_in,
                              void* d_out, int out_size, void* d_ws, size_t ws_size,
                              hipStream_t stream) {
    const float* z   = (const float*)d_in[0];
    const float* emb = (const float*)d_in[1];
    float* out = (float*)d_out;

    char* ws = (char*)d_ws;
    float* inv_norm = (float*)ws;                                   // 32 KB
    unsigned long long* cand = (unsigned long long*)(ws + 32768);   // 8 MB
    float* loss_tok = (float*)(ws + 32768 + (size_t)8*1024*1024);   // 32 KB
    short* z_hi = (short*)(ws + 65536 + (size_t)8*1024*1024);       // 8 MB
    short* e_hi = z_hi + (size_t)FCB * NE * CC;                     // 8 MB
    // ws needed: ~24.1 MB (previous rounds used 33.7 MB successfully)

    init_kernel<<<ROWS, 256, 0, stream>>>(emb, inv_norm);
    pack_hi<<<4096, 256, 0, stream>>>(z, emb, z_hi, e_hi);
    gemm_sel<<<dim3(NE/128, NE/128, FCB), 256, 0, stream>>>(z_hi, e_hi, inv_norm, cand);
    rescore_epilogue<<<TOKENS/4, 256, 0, stream>>>(z, emb, inv_norm, cand, out, loss_tok);
    loss_reduce<<<1, 256, 0, stream>>>(loss_tok, out);
}

// Round 6
// 143.227 us; speedup vs baseline: 1.7154x; 1.1370x over previous
//
#include <hip/hip_runtime.h>
#include <hip/hip_bf16.h>
#include <stdint.h>

// Problem constants (fixed by setup_inputs)
#define FCB 2            // codebooks
#define BB 16            // batch
#define NN 256           // tokens per (b)
#define EDIM 1024
#define CC 512           // channels per codebook
#define NE 4096          // prototypes per codebook
#define TOKENS (BB*FCB*NN)   // 8192
#define ROWS (FCB*NE)        // 8192 emb rows
#define OUT_LOSS (BB*NN*EDIM)   // 4194304 (also the element count for the mean)
#define OUT_IDX  (OUT_LOSS + 1)
#define MARGIN 0.15f     // rescore margin, v-units (v = z.e/||e|| ~ 22.6*cos); ~24 sigma of bf16 noise

typedef __attribute__((ext_vector_type(8))) short bf16x8;   // MFMA A/B frag (4 VGPRs)
typedef __attribute__((ext_vector_type(4))) float f32x4;    // 16x16 MFMA C/D frag

// monotonic float<->uint mapping for packed argmax
__device__ __forceinline__ unsigned int ford(float v) {
    unsigned int u = __float_as_uint(v);
    return (u & 0x80000000u) ? ~u : (u | 0x80000000u);
}
__device__ __forceinline__ float unford(unsigned int u) {
    unsigned int b = (u & 0x80000000u) ? (u & 0x7fffffffu) : ~u;
    return __uint_as_float(b);
}

// ---------------------------------------------------------------------------
// ws layout:
//   [0]        norm_sq   8192 f32                   (32 KB)  memset 0, atomic-accumulated
//   [32768]    cand      8192 tok x 64 slots x 2 u32 (4 MB)  top-2 per 64-col group
//   [32768+4M] loss_tok  8192 f32                   (32 KB)
//   [+32KB]    z_hi      2*4096*512 bf16            (8 MB)   fragment-packed
//   [+8MB]     e_hi      2*4096*512 bf16            (8 MB)
// Packed layout: elem = ((f*256 + R)*64 + Q)*128 + m*8 + j
//   (R = 16-row tile, Q = 8-elem k-chunk, m = row-in-tile, j = elem).
//   One 1-KB staging chunk = (R, qb..qb+3) = 16 rows x 32 k; both the
//   global_load_lds staging and ds_read_b128 fragment reads are lane-linear
//   (lane <-> 16 B), conflict-free.  (R3/R5-proven layout.)
// ---------------------------------------------------------------------------

// ---- pack: fp32 -> bf16 hi, fragment-packed; emb blocks also accumulate ----
// per-row norm^2 partials into norm_sq (selection-only precision).
__global__ __launch_bounds__(256) void pack_hi(
    const float* __restrict__ z, const float* __restrict__ emb,
    short* __restrict__ z_hi, short* __restrict__ e_hi,
    float* __restrict__ norm_sq)
{
    __shared__ float red[256];
    int bid = blockIdx.x;
    int tid = threadIdx.x;
    bool is_emb = (bid >= 2048);
    const float* src; short* hi; int RS, FRO, FCO;
    if (!is_emb) { src = z;   hi = z_hi; RS = EDIM; FRO = 0;  FCO = CC; }
    else         { src = emb; hi = e_hi; RS = CC;   FRO = NE; FCO = 0; bid -= 2048; }
    int u = bid * 256 + tid;                  // [0, 524288)
    int m = u & 15;
    int Q = (u >> 4) & 63;
    int R = (u >> 10) & 255;
    int f = u >> 18;
    int row = R * 16 + m;
    const float* s = src + (size_t)(f * FRO + row) * RS + f * FCO + Q * 8;
    float4 v0 = *(const float4*)s;
    float4 v1 = *(const float4*)(s + 4);
    float vv[8] = {v0.x, v0.y, v0.z, v0.w, v1.x, v1.y, v1.z, v1.w};
    bf16x8 h8;
    float ss = 0.f;
    #pragma unroll
    for (int j = 0; j < 8; ++j) {
        __hip_bfloat16 hb = __float2bfloat16(vv[j]);
        h8[j] = *(short*)&hb;
        ss = fmaf(vv[j], vv[j], ss);
    }
    *(bf16x8*)(hi + (size_t)u * 8) = h8;

    if (is_emb) {
        // block covers 16 rows x 128 k-elems; reduce over the 16 Q-threads/row
        red[tid] = ss;
        __syncthreads();
        if (tid < 16) {
            float t = 0.f;
            #pragma unroll
            for (int q = 0; q < 16; ++q) t += red[tid + 16 * q];
            int bf = (bid * 256) >> 18;
            int bR = ((bid * 256) >> 10) & 255;
            atomicAdd(norm_sq + bf * NE + bR * 16 + tid, t);
        }
    }
}

// ---- 1-product bf16 MFMA GEMM (BK=64) + per-token top-2-per-64col select ---
// 128x128 block, 4 waves (2x2), wave = 64x64 = 4x4 tiles of 16x16x32.
__global__ __launch_bounds__(256, 3) void gemm_sel(
    const short* __restrict__ zh, const short* __restrict__ eh,
    const float* __restrict__ norm_sq, unsigned int* __restrict__ cand)
{
    __shared__ char smem[32768];      // A 16K | B 16K (tile-major, [tile][h][1KB])
    const int f  = blockIdx.z;
    const int t0 = blockIdx.y * 128;  // token base within codebook
    const int m0 = blockIdx.x * 128;  // proto base within codebook
    const int tid  = threadIdx.x;
    const int wave = tid >> 6, lane = tid & 63;
    const int wm = wave & 1, wn = wave >> 1;

    f32x4 acc[4][4] = {};

    for (int step = 0; step < 8; ++step) {
        __syncthreads();              // previous compute done before overwrite
        // 32 chunks of 1 KB per step: A (c<16), B (c>=16); wave stages 8
        #pragma unroll
        for (int i = 0; i < 8; ++i) {
            int c = wave * 8 + i;
            const short* gsrc = (c < 16) ? zh : eh;
            int cl = c & 15;
            int Rl = cl >> 1, h = cl & 1;
            int R = ((c < 16) ? (t0 >> 4) : (m0 >> 4)) + Rl;
            int qb = step * 8 + h * 4;
            const short* g = gsrc
                + (((size_t)f * 256 + R) * 64 + qb) * 128 + (size_t)lane * 8;
            __builtin_amdgcn_global_load_lds(
                (const __attribute__((address_space(1))) void*)g,
                (__attribute__((address_space(3))) void*)(smem + c * 1024),
                16, 0, 0);
        }
        __syncthreads();              // staged data visible to all waves

        #pragma unroll
        for (int h = 0; h < 2; ++h) {
            bf16x8 ah[4], bh[4];
            #pragma unroll
            for (int i = 0; i < 4; ++i) {
                ah[i] = *(const bf16x8*)(smem + ((wm*4 + i)*2 + h) * 1024 + lane * 16);
                bh[i] = *(const bf16x8*)(smem + 16384 + ((wn*4 + i)*2 + h) * 1024 + lane * 16);
            }
            #pragma unroll
            for (int i = 0; i < 4; ++i)
                #pragma unroll
                for (int j2 = 0; j2 < 4; ++j2)
                    acc[i][j2] = __builtin_amdgcn_mfma_f32_16x16x32_bf16(ah[i], bh[j2], acc[i][j2], 0, 0, 0);
        }
    }

    // ---- selection epilogue: per token, top-2 over this wave's 64 cols ----
    // C/D layout (16x16x32): col = lane&15, row = (lane>>4)*4 + reg
    // u32 pack: score high bits | (col_local ^ 63)  (tie -> lower col wins;
    // truncation error <= 2e-4 absorbed by MARGIN; exact rescore follows)
    float inm[4]; unsigned ccode[4];
    #pragma unroll
    for (int j2 = 0; j2 < 4; ++j2) {
        int col = j2 * 16 + (lane & 15);              // [0,64) within wave group
        ccode[j2] = (unsigned)(col ^ 63);
        inm[j2] = rsqrtf(norm_sq[f * NE + m0 + wn * 64 + col]);
    }

    #pragma unroll
    for (int i = 0; i < 4; ++i) {
        #pragma unroll
        for (int r = 0; r < 4; ++r) {
            unsigned p1 = 0u, p2 = 0u;
            #pragma unroll
            for (int j2 = 0; j2 < 4; ++j2) {
                float w = acc[i][j2][r] * inm[j2];
                unsigned pw = (ford(w) & 0xFFFFFFC0u) | ccode[j2];
                if (pw > p1) { p2 = p1; p1 = pw; }
                else if (pw > p2) p2 = pw;
            }
            // merge top-2 across the 16 contiguous lanes of this token row
            #pragma unroll
            for (int off = 8; off; off >>= 1) {
                unsigned q1 = __shfl_down(p1, off, 16);
                unsigned q2 = __shfl_down(p2, off, 16);
                if (q1 > p1) { unsigned t = p1; p1 = q1; p2 = (t > q2) ? t : q2; }
                else         { p2 = (p2 > q1) ? p2 : q1; }
            }
            if ((lane & 15) == 0) {
                int u = t0 + wm * 64 + i * 16 + (lane >> 4) * 4 + r;
                int b = u >> 8, n = u & 255;
                int gt = ((b * FCB + f) << 8) + n;   // global token id (b,f,n)
                int s = (blockIdx.x << 1) | wn;      // slot covers cols s*64..
                uint2 val; val.x = p1; val.y = p2;
                *(uint2*)(cand + ((size_t)gt << 7) + (s << 1)) = val;
            }
        }
    }
}

// ---- rescore + output epilogue: one wave per token (exact norms in-kernel) -
__global__ __launch_bounds__(256) void rescore_epilogue(
    const float* __restrict__ z, const float* __restrict__ emb,
    const unsigned int* __restrict__ cand,
    float* __restrict__ out, float* __restrict__ loss_tok)
{
    int t = blockIdx.x * 4 + (threadIdx.x >> 6);   // global token (b,f,n)
    int lane = threadIdx.x & 63;
    int n = t & 255;
    int f = (t >> 8) & 1;
    int b = t >> 9;
    const float* zrow = z + ((size_t)(b*NN + n))*EDIM + f*CC;
    float4 za = *(const float4*)(zrow + lane * 8);
    float4 zb = *(const float4*)(zrow + lane * 8 + 4);

    // 128 candidates: lane reads slot s == lane (2 packed u32)
    uint2 cc = *(const uint2*)(cand + ((size_t)t << 7) + (lane << 1));
    unsigned c1 = cc.x, c2 = cc.y;

    unsigned m1 = (c1 > c2) ? c1 : c2;
    #pragma unroll
    for (int off = 32; off; off >>= 1) {
        unsigned o = __shfl_xor(m1, off);
        if (o > m1) m1 = o;
    }
    float thr = unford(m1) - MARGIN;

    unsigned long long bestp = 0ull;
    #pragma unroll
    for (int rnd = 0; rnd < 2; ++rnd) {
        unsigned u = rnd ? c2 : c1;
        float v = unford(u);
        unsigned long long mask = __ballot(v > thr);
        while (mask) {
            int src = __ffsll((long long)mask) - 1;
            mask &= mask - 1;
            unsigned cu = __shfl(u, src);
            int idx = (src << 6) | ((int)(cu & 63u) ^ 63);   // proto index [0,4096)
            const float* er = emb + ((size_t)(f * NE + idx)) * CC;
            float4 ea = *(const float4*)(er + lane * 8);
            float4 eb = *(const float4*)(er + lane * 8 + 4);
            float d  = za.x*ea.x + za.y*ea.y + za.z*ea.z + za.w*ea.w
                     + zb.x*eb.x + zb.y*eb.y + zb.z*eb.z + zb.w*eb.w;
            float se = ea.x*ea.x + ea.y*ea.y + ea.z*ea.z + ea.w*ea.w
                     + eb.x*eb.x + eb.y*eb.y + eb.z*eb.z + eb.w*eb.w;
            #pragma unroll
            for (int off = 32; off; off >>= 1) {
                d  += __shfl_xor(d, off);
                se += __shfl_xor(se, off);
            }
            float vex = d / fmaxf(sqrtf(se), 1e-12f);        // exact score
            unsigned long long pex = ((unsigned long long)ford(vex) << 32)
                                   | (unsigned int)(~(unsigned int)idx);
            if (pex > bestp) bestp = pex;
        }
    }
    int idxb = (int)(~(unsigned int)bestp);    // exact argmax (tie -> lower idx)

    // ---- output: z_q gather (codebook-0 row, faithful quirk) + loss -------
    const float* er0 = emb + (size_t)idxb * CC;
    float4 ea = *(const float4*)(er0 + lane * 8);
    float4 eb = *(const float4*)(er0 + lane * 8 + 4);
    float se0 = ea.x*ea.x + ea.y*ea.y + ea.z*ea.z + ea.w*ea.w
              + eb.x*eb.x + eb.y*eb.y + eb.z*eb.z + eb.w*eb.w;
    #pragma unroll
    for (int off = 32; off; off >>= 1) se0 += __shfl_xor(se0, off);
    float inm0 = 1.0f / fmaxf(sqrtf(se0), 1e-12f);
    float* orow = out + ((size_t)(b*NN + n))*EDIM + f*CC;
    ea.x *= inm0; ea.y *= inm0; ea.z *= inm0; ea.w *= inm0;
    eb.x *= inm0; eb.y *= inm0; eb.z *= inm0; eb.w *= inm0;
    *(float4*)(orow + lane * 8) = ea;
    *(float4*)(orow + lane * 8 + 4) = eb;
    float s1 = za.x*za.x + za.y*za.y + za.z*za.z + za.w*za.w
             + zb.x*zb.x + zb.y*zb.y + zb.z*zb.z + zb.w*zb.w;
    float s2 = za.x*ea.x + za.y*ea.y + za.z*ea.z + za.w*ea.w
             + zb.x*eb.x + zb.y*eb.y + zb.z*eb.z + zb.w*eb.w;
    #pragma unroll
    for (int off = 32; off; off >>= 1) {
        s1 += __shfl_xor(s1, off);
        s2 += __shfl_xor(s2, off);
    }
    if (lane == 0) {
        float cosv = s2 / fmaxf(sqrtf(s1), 1e-12f);   // zn . z_q
        loss_tok[t] = 2.0f - 2.0f * cosv;
        out[OUT_IDX + t] = (float)idxb;               // indices read back as float
    }
}

// ---- final: sum per-token losses -> out[OUT_LOSS] --------------------------
__global__ __launch_bounds__(256) void loss_reduce(
    const float* __restrict__ loss_tok, float* __restrict__ out)
{
    int tid = threadIdx.x;
    float s = 0.f;
    #pragma unroll
    for (int h = 0; h < 32; ++h) s += loss_tok[h * 256 + tid];
    #pragma unroll
    for (int off = 32; off; off >>= 1) s += __shfl_down(s, off);
    __shared__ float part[4];
    if ((tid & 63) == 0) part[tid >> 6] = s;
    __syncthreads();
    if (tid == 0) {
        float t = part[0] + part[1] + part[2] + part[3];
        out[OUT_LOSS] = t * (1.25f / (float)OUT_LOSS);
    }
}

extern "C" void kernel_launch(void* const* d_in, const int* in_sizes, int n_in,
                              void* d_out, int out_size, void* d_ws, size_t ws_size,
                              hipStream_t stream) {
    const float* z   = (const float*)d_in[0];
    const float* emb = (const float*)d_in[1];
    float* out = (float*)d_out;

    char* ws = (char*)d_ws;
    float* norm_sq = (float*)ws;                                    // 32 KB
    unsigned int* cand = (unsigned int*)(ws + 32768);               // 4 MB
    float* loss_tok = (float*)(ws + 32768 + (size_t)4*1024*1024);   // 32 KB
    short* z_hi = (short*)(ws + 65536 + (size_t)4*1024*1024);       // 8 MB
    short* e_hi = z_hi + (size_t)FCB * NE * CC;                     // 8 MB
    // ws needed: ~20.1 MB

    hipMemsetAsync(norm_sq, 0, ROWS * sizeof(float), stream);
    pack_hi<<<4096, 256, 0, stream>>>(z, emb, z_hi, e_hi, norm_sq);
    gemm_sel<<<dim3(NE/128, NE/128, FCB), 256, 0, stream>>>(z_hi, e_hi, norm_sq, cand);
    rescore_epilogue<<<TOKENS/4, 256, 0, stream>>>(z, emb, cand, out, loss_tok);
    loss_reduce<<<1, 256, 0, stream>>>(loss_tok, out);
}